// Round 3
// baseline (43.297 us; speedup 1.0000x reference)
//
#include <hip/hip_runtime.h>
#include <math.h>

// Problem constants (fixed by the reference)
constexpr int B_    = 8;
constexpr int CIN_  = 128;
constexpr int H_    = 28;
constexpr int W_    = 28;
constexpr int COUT_ = 256;
constexpr int OH_   = 28;
constexpr int OW_   = 28;
constexpr int L_    = OH_ * OW_;     // 784
constexpr int N_    = B_ * L_;       // 6272
constexpr int NCB_  = 64;
constexpr int K_    = 16;
constexpr int SUB_  = 18;            // 2 channels x 9 taps

typedef short v4s __attribute__((ext_vector_type(4)));

// ws layout (bytes):
constexpr size_t WS_IDX  = 0;                    // 64*6272*4 = 1.606 MB
constexpr size_t WS_LUT  = 2u << 20;             // 262144 shorts = 512 KB
constexpr size_t WS_CF   = 3u << 20;             // 64*16*18 floats = 72 KB
constexpr size_t WS_Y2   = (3u << 20) + (512u << 10); // 64*16 floats = 4 KB

// ---------------------------------------------------------------------------
// Pre-pass: pack LUT int32 -> int16; centroids -> float(c_q - c_z); y2 -> f32.
// Blocks 0..255 pack the LUT (1024 elems each); blocks 256..259 do centroids.
// ---------------------------------------------------------------------------
__global__ __launch_bounds__(256) void amm_pack(
    const int* __restrict__ lut_q,
    const int* __restrict__ c_q, const float* __restrict__ c_s,
    const int* __restrict__ c_z, const float* __restrict__ x_s,
    short* __restrict__ lut16, float* __restrict__ cf, float* __restrict__ y2f)
{
    const int bid = blockIdx.x, tid = threadIdx.x;
    if (bid < 256) {
        const int i = bid * 1024 + tid * 4;      // covers 262144 exactly
        const int4 v = *(const int4*)(lut_q + i);
        v4s o; o.x = (short)v.x; o.y = (short)v.y; o.z = (short)v.z; o.w = (short)v.w;
        *(v4s*)(lut16 + i) = o;
    } else {
        const int t = (bid - 256) * 256 + tid;   // (cb,k) pair
        if (t >= NCB_ * K_) return;
        const int cb = t >> 4;
        const int zc = c_z[cb];
        const double csf = (double)c_s[cb];
        const double den = (double)x_s[0] * csf;
        double s2 = 0.0;
        for (int s = 0; s < SUB_; ++s) {
            const int ci = c_q[t * SUB_ + s] - zc;
            cf[t * SUB_ + s] = (float)ci;        // exact small integer
            const double d = (double)ci * csf;
            s2 += d * d;
        }
        y2f[t] = (float)(int)rint(s2 / den);     // < 2^24 -> exact in f32
    }
}

// ---------------------------------------------------------------------------
// Phase 1: per (codebook, position) argmin over 16 centroids.
// dist = y2f[k] - 2*dot, dot = sum xi * (c_q - zc)  (exact integers in f32).
// Centroid addresses are block-uniform -> scalar loads, fmac with SGPR src.
// ---------------------------------------------------------------------------
__global__ __launch_bounds__(256) void amm_phase1(
    const int* __restrict__ x_q, const int* __restrict__ x_z,
    const float* __restrict__ cf, const float* __restrict__ y2f,
    int* __restrict__ idx_out)
{
    const int cb  = blockIdx.x;
    const int tid = threadIdx.x;
    const int n   = blockIdx.y * 256 + tid;
    if (n >= N_) return;

    const float* __restrict__ crow = cf  + cb * (K_ * SUB_);
    const float* __restrict__ yrow = y2f + cb * K_;

    const int xz = x_z[0];
    const int b  = n / L_;
    const int r  = n - b * L_;
    const int oh = r / OW_;
    const int ow = r - oh * OW_;

    float xi[SUB_];
    #pragma unroll
    for (int c2 = 0; c2 < 2; ++c2) {
        const int* base = x_q + (size_t)(b * CIN_ + 2 * cb + c2) * (H_ * W_);
        #pragma unroll
        for (int kh = 0; kh < 3; ++kh) {
            const int h = oh + kh - 1;
            #pragma unroll
            for (int kw = 0; kw < 3; ++kw) {
                const int w = ow + kw - 1;
                int v = 0;
                if ((unsigned)h < (unsigned)H_ && (unsigned)w < (unsigned)W_)
                    v = base[h * W_ + w] - xz;
                xi[c2 * 9 + kh * 3 + kw] = (float)v;
            }
        }
    }

    float bestd = 3.0e38f;
    int   bestk = 0;
    #pragma unroll
    for (int k = 0; k < K_; ++k) {
        float dot = 0.0f;
        #pragma unroll
        for (int s = 0; s < SUB_; ++s)
            dot = fmaf(xi[s], crow[k * SUB_ + s], dot);
        const float d = fmaf(-2.0f, dot, yrow[k]);   // exact integer-valued
        if (d < bestd) { bestd = d; bestk = k; }     // strict < => first min
    }
    idx_out[cb * N_ + n] = bestk;
}

// ---------------------------------------------------------------------------
// Phase 2: out[n][co] = relu( (sum_cb lut[cb][idx][co] - 64*lz)*ls
//                             + (bias_q[co]-bz)*bs ), requantized to int8
// written as int32. Block = 4 positions x 64 lanes; 4 couts/lane; int16 LUT
// accumulated as <4 x i16> (v_pk_add_i16), |sum| <= 8192 so no overflow.
// ---------------------------------------------------------------------------
__global__ __launch_bounds__(256) void amm_phase2(
    const int* __restrict__ idx_in, const short* __restrict__ lut16,
    const float* __restrict__ lut_s, const int* __restrict__ lut_z,
    const int* __restrict__ bias_q, const float* __restrict__ bias_s,
    const int* __restrict__ bias_z,
    const float* __restrict__ out_s, const int* __restrict__ out_z,
    int* __restrict__ out)
{
    const int tid = threadIdx.x;
    const int nb  = blockIdx.x * 4;

    __shared__ int sidx[4][NCB_];
    {
        const int cbb = tid & 63, j = tid >> 6;
        sidx[j][cbb] = idx_in[cbb * N_ + nb + j];
    }
    __syncthreads();

    const int j    = tid >> 6;
    const int lane = tid & 63;
    const int n    = nb + j;

    const v4s* lut4 = (const v4s*)lut16;   // 64 v4s (= 256 shorts) per (cb,k) row
    v4s acc = {0, 0, 0, 0};
    #pragma unroll 16
    for (int cb = 0; cb < NCB_; ++cb) {
        const int k = sidx[j][cb];
        acc += lut4[(cb * K_ + k) * 64 + lane];
    }

    const float lsf = lut_s[0];
    const int   lz  = lut_z[0];
    const float bsf = bias_s[0];
    const int   bz  = bias_z[0];
    const float osf = out_s[0];
    const float ozf = (float)out_z[0];

    const int b = n / L_;
    const int r = n - b * L_;

    const int accs[4] = {(int)acc.x, (int)acc.y, (int)acc.z, (int)acc.w};
    #pragma unroll
    for (int i = 0; i < 4; ++i) {
        const int co = lane * 4 + i;
        float sum = (float)(accs[i] - NCB_ * lz) * lsf
                  + (float)(bias_q[co] - bz) * bsf;
        float o = fmaxf(sum, 0.0f);                 // ReLU
        float v = o / osf + ozf;
        v = fminf(fmaxf(v, -128.0f), 127.0f);
        out[(size_t)(b * COUT_ + co) * L_ + r] = (int)rintf(v);
    }
}

extern "C" void kernel_launch(void* const* d_in, const int* in_sizes, int n_in,
                              void* d_out, int out_size, void* d_ws, size_t ws_size,
                              hipStream_t stream)
{
    const int*   x_q    = (const int*)  d_in[0];
    const float* x_s    = (const float*)d_in[1];
    const int*   x_z    = (const int*)  d_in[2];
    const int*   c_q    = (const int*)  d_in[3];
    const float* c_s    = (const float*)d_in[4];
    const int*   c_z    = (const int*)  d_in[5];
    const int*   lut_q  = (const int*)  d_in[6];
    const float* lut_s  = (const float*)d_in[7];
    const int*   lut_z  = (const int*)  d_in[8];
    const int*   bias_q = (const int*)  d_in[9];
    const float* bias_s = (const float*)d_in[10];
    const int*   bias_z = (const int*)  d_in[11];
    const float* out_s  = (const float*)d_in[12];
    const int*   out_z  = (const int*)  d_in[13];

    char* ws = (char*)d_ws;
    int*   idx_ws = (int*)  (ws + WS_IDX);
    short* lut16  = (short*)(ws + WS_LUT);
    float* cfp    = (float*)(ws + WS_CF);
    float* y2fp   = (float*)(ws + WS_Y2);

    amm_pack<<<dim3(260), 256, 0, stream>>>(lut_q, c_q, c_s, c_z, x_s,
                                            lut16, cfp, y2fp);

    dim3 g1(NCB_, (N_ + 255) / 256);
    amm_phase1<<<g1, 256, 0, stream>>>(x_q, x_z, cfp, y2fp, idx_ws);

    amm_phase2<<<dim3(N_ / 4), 256, 0, stream>>>(
        idx_ws, lut16, lut_s, lut_z, bias_q, bias_s, bias_z,
        out_s, out_z, (int*)d_out);
}